// Round 9
// baseline (311.469 us; speedup 1.0000x reference)
//
#include <hip/hip_runtime.h>
#include <stdint.h>

#define N_NODES 6144
#define LOG2E 1.44269504088896f

typedef float f32x4 __attribute__((ext_vector_type(4)));
typedef short short8 __attribute__((ext_vector_type(8)));
typedef unsigned int uint32;

extern "C" __device__ float __ocml_native_exp2_f32(float);

// pack two floats -> two bf16 (round-half-up) in one u32: lo=a, hi=b
__device__ __forceinline__ unsigned int pack2bf(float a, float b) {
  unsigned int ua = __float_as_uint(a) + 0x8000u;
  unsigned int ub = __float_as_uint(b) + 0x8000u;
  return __builtin_amdgcn_perm(ub, ua, 0x07060302u);
}

// K1: h = x*W (fp32). hfT (bf16 [c][n]) coalesced via LDS transpose;
// s_src2/s_dst2 = (h . a_{src,dst}) * log2(e).
__global__ __launch_bounds__(256) void k1_feat(const float* __restrict__ x,
                                               const float* __restrict__ W,
                                               const float* __restrict__ a,
                                               unsigned short* __restrict__ hfT,
                                               float* __restrict__ s_src2,
                                               float* __restrict__ s_dst2) {
  __shared__ float xl[64][132];
  __shared__ float Wl[64][128];
  int t = threadIdx.x;
  int n0 = blockIdx.x * 64;
  for (int u = t; u < 2048; u += 256) {
    int row = u >> 5, c4 = (u & 31) << 2;
    *(float4*)&xl[row][c4] = *(const float4*)(x + (size_t)(n0 + row) * 128 + c4);
  }
  int cg = t & 31, c0 = cg << 2;
  int ng = t >> 5, nb = ng << 3;
  float acc[8][4] = {};
  for (int ic = 0; ic < 2; ++ic) {
    __syncthreads();
    for (int u = t; u < 2048; u += 256) {
      int ii = u >> 5, c4 = (u & 31) << 2;
      int hh = c4 >> 5, d0 = c4 & 31;
      *(float4*)&Wl[ii][c4] = *(const float4*)(W + hh * 4096 + (ic * 64 + ii) * 32 + d0);
    }
    __syncthreads();
    #pragma unroll 4
    for (int ii = 0; ii < 64; ++ii) {
      float4 wv = *(float4*)&Wl[ii][c0];
      int i = ic * 64 + ii;
      #pragma unroll
      for (int r = 0; r < 8; ++r) {
        float xv = xl[nb + r][i];
        acc[r][0] += xv * wv.x; acc[r][1] += xv * wv.y;
        acc[r][2] += xv * wv.z; acc[r][3] += xv * wv.w;
      }
    }
  }
  __syncthreads();
  unsigned short* tb = (unsigned short*)&xl[0][0];   // bf16 [128][66]
  float* pb = &Wl[0][0];                             // float [2][64][33]
  int hh = c0 >> 5, d0 = c0 & 31;
  float4 adv = *(const float4*)(a + hh * 64 + d0);
  float4 asv = *(const float4*)(a + hh * 64 + 32 + d0);
  #pragma unroll
  for (int cc = 0; cc < 4; ++cc) {
    unsigned int* dst = (unsigned int*)(tb + (c0 + cc) * 66 + nb);
    #pragma unroll
    for (int p = 0; p < 4; ++p)
      dst[p] = pack2bf(acc[2 * p][cc], acc[2 * p + 1][cc]);
  }
  #pragma unroll
  for (int r = 0; r < 8; ++r) {
    float pd = acc[r][0] * adv.x + acc[r][1] * adv.y + acc[r][2] * adv.z + acc[r][3] * adv.w;
    float ps = acc[r][0] * asv.x + acc[r][1] * asv.y + acc[r][2] * asv.z + acc[r][3] * asv.w;
    pb[(nb + r) * 33 + cg] = pd;
    pb[2112 + (nb + r) * 33 + cg] = ps;
  }
  __syncthreads();
  {
    int row = t >> 1, half = t & 1;
    const unsigned int* s32 = (const unsigned int*)(tb + row * 66 + half * 32);
    unsigned int v[16];
    #pragma unroll
    for (int q = 0; q < 16; ++q) v[q] = s32[q];
    unsigned short* gdst = hfT + (size_t)row * N_NODES + n0 + half * 32;
    #pragma unroll
    for (int q = 0; q < 4; ++q) {
      uint4 w4; w4.x = v[4 * q]; w4.y = v[4 * q + 1]; w4.z = v[4 * q + 2]; w4.w = v[4 * q + 3];
      *(uint4*)(gdst + q * 8) = w4;
    }
  }
  for (int task = t; task < 512; task += 256) {
    int n = task & 63, hz = task >> 6;
    int h = hz & 3, sdx = hz >> 2;
    const float* src = pb + sdx * 2112 + n * 33 + h * 8;
    float s = src[0] + src[1] + src[2] + src[3] + src[4] + src[5] + src[6] + src[7];
    float* out = sdx ? s_src2 : s_dst2;
    out[h * N_NODES + n0 + n] = s * LOG2E;
  }
}

// one m-tile k-step: 16x32 A-fragment weights in-register, 2 MFMAs + z tree
__device__ __forceinline__ void gat_tile(float ss, uint32 bits8,
                                         const float (&dv)[8], short8 b0, short8 b1,
                                         f32x4& a0, f32x4& a1, float& zacc) {
  float w[8];
  #pragma unroll
  for (int j = 0; j < 8; ++j) {
    float e = ss + dv[j];                    // (s_src+s_dst) * log2e
    float lr = fmaxf(e, 0.2f * e);           // leaky-relu (log2 domain)
    float ex = __ocml_native_exp2_f32(lr);   // v_exp_f32
    w[j] = (bits8 & (1u << j)) ? ex : 0.f;
  }
  zacc += ((w[0] + w[1]) + (w[2] + w[3])) + ((w[4] + w[5]) + (w[6] + w[7]));
  union { uint32 u4[4]; short8 v; } afr;
  #pragma unroll
  for (int j = 0; j < 4; ++j) afr.u4[j] = pack2bf(w[2 * j], w[2 * j + 1]);
  a0 = __builtin_amdgcn_mfma_f32_16x16x32_bf16(afr.v, b0, a0, 0, 0, 0);
  a1 = __builtin_amdgcn_mfma_f32_16x16x32_bf16(afr.v, b1, a1, 0, 0, 0);
}

// K2: fully-fused masked-softmax aggregate with in-kernel adjacency packing.
// Block = 4 waves = 4 heads x 64 rows (4 m-tiles) x k-slice 768 (split 8),
// processed as 3 chunks of 256 k. Per chunk: stage adj(HBM,64KB)->2.3KB LDS
// bitmask, hfT(L2,64KB)->LDS, s_dst->LDS; then 8 fully-unrolled k-steps of
// pure LDS+VALU+MFMA (zero global traffic in the inner loop).
__global__ __launch_bounds__(256) void k2_attn(const int* __restrict__ adj,
                                               const unsigned short* __restrict__ hfT,
                                               const float* __restrict__ s_src2,
                                               const float* __restrict__ s_dst2,
                                               float* __restrict__ Zpart,
                                               float* __restrict__ part) {
  __shared__ unsigned short hfl[128 * 264];   // 67.6 KB, row stride 264 (+8 pad)
  __shared__ uint32 ml[64 * 9];               // 2.3 KB, row stride 9
  __shared__ float sdl[4 * 256];              // 4 KB
  int t = threadIdx.x;
  int h = t >> 6, lane = t & 63, m = lane & 15, quad = lane >> 4;
  int sh = quad << 3;
  int bx = blockIdx.x;
  int slice = bx & 7, mg = bx >> 3;
  int i0 = mg << 6;                 // 64 rows
  int kb0 = slice * 768;            // 3 chunks of 256

  float ss0 = s_src2[h * N_NODES + i0 + m];
  float ss1 = s_src2[h * N_NODES + i0 + 16 + m];
  float ss2 = s_src2[h * N_NODES + i0 + 32 + m];
  float ss3 = s_src2[h * N_NODES + i0 + 48 + m];

  f32x4 a00 = {0,0,0,0}, a01 = {0,0,0,0};
  f32x4 a10 = {0,0,0,0}, a11 = {0,0,0,0};
  f32x4 a20 = {0,0,0,0}, a21 = {0,0,0,0};
  f32x4 a30 = {0,0,0,0}, a31 = {0,0,0,0};
  float z0 = 0.f, z1 = 0.f, z2 = 0.f, z3 = 0.f;

  // staging index sets (chunk-invariant)
  int s_row = t >> 1, s_half = t & 1;            // hfT: 2 thr/row, 128B halves
  int a_row = t >> 2, a_wq = t & 3;              // adj: 4 thr/row, 64-col quarters
  int d_h = t >> 6, d_k = (t & 63) << 2;         // sd: 1 float4/thread

  for (int c = 0; c < 3; ++c) {
    int kb = kb0 + (c << 8);
    if (c) __syncthreads();   // prior chunk's LDS reads done
    // --- stage hfT chunk: [128 rows][256 k] -> hfl[row*264 + k]
    {
      const unsigned short* g = hfT + (size_t)s_row * N_NODES + kb + (s_half << 7);
      unsigned short* l = hfl + s_row * 264 + (s_half << 7);
      #pragma unroll
      for (int i = 0; i < 16; ++i)
        *(int4*)(l + (i << 3)) = *(const int4*)(g + (i << 3));
    }
    // --- stage + pack adj chunk: rows i0..i0+63, cols kb..kb+255
    {
      const int* g = adj + (size_t)(i0 + a_row) * N_NODES + kb + (a_wq << 6);
      uint32 w0 = 0, w1 = 0;
      #pragma unroll
      for (int i = 0; i < 8; ++i) {
        int4 v = *(const int4*)(g + (i << 2));
        int bb = i << 2;
        w0 |= (v.x != 0 ? 1u : 0u) << bb;
        w0 |= (v.y != 0 ? 1u : 0u) << (bb + 1);
        w0 |= (v.z != 0 ? 1u : 0u) << (bb + 2);
        w0 |= (v.w != 0 ? 1u : 0u) << (bb + 3);
      }
      #pragma unroll
      for (int i = 8; i < 16; ++i) {
        int4 v = *(const int4*)(g + (i << 2));
        int bb = (i - 8) << 2;
        w1 |= (v.x != 0 ? 1u : 0u) << bb;
        w1 |= (v.y != 0 ? 1u : 0u) << (bb + 1);
        w1 |= (v.z != 0 ? 1u : 0u) << (bb + 2);
        w1 |= (v.w != 0 ? 1u : 0u) << (bb + 3);
      }
      ml[a_row * 9 + (a_wq << 1)] = w0;
      ml[a_row * 9 + (a_wq << 1) + 1] = w1;
    }
    // --- stage s_dst chunk
    *(float4*)&sdl[d_h * 256 + d_k] =
        *(const float4*)(s_dst2 + d_h * N_NODES + kb + d_k);
    __syncthreads();

    // --- inner: 8 k-steps, pure LDS
    const unsigned short* hb0 = hfl + (h * 32 + m) * 264 + sh;
    const unsigned short* hb1 = hb0 + 16 * 264;
    const float* sdp = sdl + h * 256 + sh;
    const uint32* m0p = ml + (0 * 16 + m) * 9;
    const uint32* m1p = ml + (1 * 16 + m) * 9;
    const uint32* m2p = ml + (2 * 16 + m) * 9;
    const uint32* m3p = ml + (3 * 16 + m) * 9;
    #pragma unroll
    for (int kt = 0; kt < 8; ++kt) {
      union { int4 i; short8 v; } b0u, b1u;
      b0u.i = *(const int4*)(hb0 + (kt << 5));
      b1u.i = *(const int4*)(hb1 + (kt << 5));
      f32x4 dd0 = *(const f32x4*)(sdp + (kt << 5));
      f32x4 dd1 = *(const f32x4*)(sdp + (kt << 5) + 4);
      float dv[8] = {dd0[0], dd0[1], dd0[2], dd0[3], dd1[0], dd1[1], dd1[2], dd1[3]};
      uint32 w0 = (m0p[kt] >> sh) & 0xffu;
      uint32 w1 = (m1p[kt] >> sh) & 0xffu;
      uint32 w2 = (m2p[kt] >> sh) & 0xffu;
      uint32 w3 = (m3p[kt] >> sh) & 0xffu;
      gat_tile(ss0, w0, dv, b0u.v, b1u.v, a00, a01, z0);
      gat_tile(ss1, w1, dv, b0u.v, b1u.v, a10, a11, z1);
      gat_tile(ss2, w2, dv, b0u.v, b1u.v, a20, a21, z2);
      gat_tile(ss3, w3, dv, b0u.v, b1u.v, a30, a31, z3);
    }
  }

  // z: reduce quad partials -> lanes 0-15 hold row sums per tile
  z0 += __shfl_xor(z0, 16); z0 += __shfl_xor(z0, 32);
  z1 += __shfl_xor(z1, 16); z1 += __shfl_xor(z1, 32);
  z2 += __shfl_xor(z2, 16); z2 += __shfl_xor(z2, 32);
  z3 += __shfl_xor(z3, 16); z3 += __shfl_xor(z3, 32);
  if (lane < 16) {
    float* zb = Zpart + h * N_NODES + i0 + m;
    atomicAdd(zb, z0);
    atomicAdd(zb + 16, z1);
    atomicAdd(zb + 32, z2);
    atomicAdd(zb + 48, z3);
  }
  // partials: (h, row, col) flat; D layout: col=lane&15, row=quad*4+reg
  float* pb = part + (size_t)h * (N_NODES * 32) + (size_t)i0 * 32;
  #pragma unroll
  for (int r = 0; r < 4; ++r) {
    int row = (quad << 2) + r;
    atomicAdd(&pb[row * 32 + m], a00[r]);
    atomicAdd(&pb[row * 32 + 16 + m], a01[r]);
    atomicAdd(&pb[(16 + row) * 32 + m], a10[r]);
    atomicAdd(&pb[(16 + row) * 32 + 16 + m], a11[r]);
    atomicAdd(&pb[(32 + row) * 32 + m], a20[r]);
    atomicAdd(&pb[(32 + row) * 32 + 16 + m], a21[r]);
    atomicAdd(&pb[(48 + row) * 32 + m], a30[r]);
    atomicAdd(&pb[(48 + row) * 32 + 16 + m], a31[r]);
  }
}

// K3: out = part / Z
__global__ __launch_bounds__(256) void k3_final(const float* __restrict__ part,
                                                const float* __restrict__ Zpart,
                                                float* __restrict__ out) {
  unsigned int idx4 = blockIdx.x * 256 + threadIdx.x;   // float4 index
  unsigned int h = idx4 / 49152u;
  unsigned int i = (idx4 - h * 49152u) >> 3;
  float rz = 1.0f / Zpart[h * N_NODES + i];
  f32x4 p = ((const f32x4*)part)[idx4];
  ((f32x4*)out)[idx4] = p * rz;
}

extern "C" void kernel_launch(void* const* d_in, const int* in_sizes, int n_in,
                              void* d_out, int out_size, void* d_ws, size_t ws_size,
                              hipStream_t stream) {
  const float* x = (const float*)d_in[0];
  const int* adj = (const int*)d_in[1];
  const float* W = (const float*)d_in[2];
  const float* a = (const float*)d_in[3];
  float* out = (float*)d_out;

  float* wsf = (float*)d_ws;
  unsigned short* hfT = (unsigned short*)wsf;       // 128*6144 bf16 (1.5 MB)
  float* s_src2 = wsf + 393216;                     // 4*6144
  float* s_dst2 = s_src2 + 24576;                   // 4*6144
  float* part   = s_dst2 + 24576;                   // 786432 (3 MB)
  float* Zpart  = part + 786432;                    // 4*6144

  (void)hipMemsetAsync(part, 0, (786432 + 24576) * sizeof(float), stream);
  hipLaunchKernelGGL(k1_feat, dim3(96), dim3(256), 0, stream, x, W, a, hfT, s_src2, s_dst2);
  hipLaunchKernelGGL(k2_attn, dim3(768), dim3(256), 0, stream,
                     adj, hfT, s_src2, s_dst2, Zpart, part);
  hipLaunchKernelGGL(k3_final, dim3(768), dim3(256), 0, stream, part, Zpart, out);
}